// Round 5
// baseline (505.094 us; speedup 1.0000x reference)
//
#include <hip/hip_runtime.h>
#include <math.h>

#define NN 20000     // nodes
#define NE 320000    // edges
#define HD 256       // hidden dim
#define EDIM 64      // edge feature dim
#define DIN 576      // 2H + ED

#define BSTRIDE 136  // LDS buffer row stride in halves (272B -> 4-bank rotation, 2-way = free)

typedef __attribute__((ext_vector_type(4))) _Float16 h4;
typedef __attribute__((ext_vector_type(8))) _Float16 h8;
typedef __attribute__((ext_vector_type(4))) float f32x4;

// fragment-ordered fp16 weights:
//   frag(cf, ks, l, j) = W[cf*16 + (l&15)][ks*32 + (l>>4)*8 + j]
__device__ _Float16 g_W1f[16 * 18 * 64 * 8];   // edge layer1: [cf][ksg<18][l][8]
__device__ _Float16 g_W2f[16 * 8  * 64 * 8];   // edge layer2
__device__ _Float16 g_Wrzf[32 * 16 * 64 * 8];  // GRU r,z combined K=512
__device__ _Float16 g_Wnxf[16 * 8  * 64 * 8];  // GRU n-gate, x side
__device__ _Float16 g_Wnhf[16 * 8  * 64 * 8];  // GRU n-gate, h side

__device__ __forceinline__ h4 f2h4(float4 v) {
  return (h4){(_Float16)v.x, (_Float16)v.y, (_Float16)v.z, (_Float16)v.w};
}

// -------------------- weight repack to fragment order --------------------
__global__ __launch_bounds__(256) void cvt_kernel(
    const float* __restrict__ W1, const float* __restrict__ W2,
    const float* __restrict__ W_ih, const float* __restrict__ W_hh)
{
  const int idx = blockIdx.x * 256 + threadIdx.x;
  const int g = idx >> 6, l = idx & 63;
  const int r16 = l & 15, koff = (l >> 4) * 8;
  if (g < 288) {                                  // W1f: cf<16, ks<18
    const int cf = g / 18, ks = g % 18;
    _Float16* dst = &g_W1f[(size_t)(cf * 18 + ks) * 64 * 8 + l * 8];
    const float* src = &W1[(size_t)(cf * 16 + r16) * DIN + ks * 32 + koff];
#pragma unroll
    for (int j = 0; j < 8; ++j) dst[j] = (_Float16)src[j];
  } else if (g < 416) {                           // W2f: cf<16, ks<8
    const int gg = g - 288, cf = gg / 8, ks = gg % 8;
    _Float16* dst = &g_W2f[(size_t)(cf * 8 + ks) * 64 * 8 + l * 8];
    const float* src = &W2[(size_t)(cf * 16 + r16) * HD + ks * 32 + koff];
#pragma unroll
    for (int j = 0; j < 8; ++j) dst[j] = (_Float16)src[j];
  } else if (g < 928) {                           // Wrzf: cf<32, ks<16, K=512 = [W_ih|W_hh]
    const int gg = g - 416, cf = gg / 16, ks = gg % 16;
    const int gr = (cf < 16) ? (cf * 16 + r16) : (256 + (cf - 16) * 16 + r16);
    const int k = ks * 32 + koff;
    const float* src = (k < 256) ? &W_ih[(size_t)gr * HD + k]
                                 : &W_hh[(size_t)gr * HD + (k - 256)];
    _Float16* dst = &g_Wrzf[(size_t)(cf * 16 + ks) * 64 * 8 + l * 8];
#pragma unroll
    for (int j = 0; j < 8; ++j) dst[j] = (_Float16)src[j];
  } else if (g < 1056) {                          // Wnxf: W_ih rows 512..767
    const int gg = g - 928, cf = gg / 8, ks = gg % 8;
    _Float16* dst = &g_Wnxf[(size_t)(cf * 8 + ks) * 64 * 8 + l * 8];
    const float* src = &W_ih[(size_t)(512 + cf * 16 + r16) * HD + ks * 32 + koff];
#pragma unroll
    for (int j = 0; j < 8; ++j) dst[j] = (_Float16)src[j];
  } else if (g < 1184) {                          // Wnhf: W_hh rows 512..767
    const int gg = g - 1056, cf = gg / 8, ks = gg % 8;
    _Float16* dst = &g_Wnhf[(size_t)(cf * 8 + ks) * 64 * 8 + l * 8];
    const float* src = &W_hh[(size_t)(512 + cf * 16 + r16) * HD + ks * 32 + koff];
#pragma unroll
    for (int j = 0; j < 8; ++j) dst[j] = (_Float16)src[j];
  }
}

// -------------------- fused edge MLP (MFMA fp16) + scatter-add --------------------
// 64 edges/block, 4 waves; wave w owns all 64 edges x cols [64w,64w+64).
// K split into 5 slices of <=128; double-buffered LDS; slice s+1 loads issued
// before slice-s MFMA (T14) so gather latency hides under compute.
__global__ __launch_bounds__(256, 4) void edge_kernel(
    const float* __restrict__ h, const int* __restrict__ ei,
    const float* __restrict__ eattr,
    const float* __restrict__ b1, const float* __restrict__ b2,
    float* __restrict__ agg)
{
  __shared__ _Float16 B0[64 * BSTRIDE];   // 17408 B
  __shared__ _Float16 B1[64 * BSTRIDE];   // 17408 B

  const int t   = threadIdx.x;
  const int w   = t >> 6;
  const int l   = t & 63;
  const int l15 = l & 15;
  const int lg  = l >> 4;
  const int e0  = blockIdx.x * 64;
  const int cg  = t >> 5;      // staging row group 0..7
  const int cl  = t & 31;      // staging float4 col within row

  float4 raw[8];

  // stage-load: 8 rows (cg+8i) x K=128 slice from h, gathered via ei
  auto loadH = [&](int which, int koff) {
    const int* idxb = ei + (which ? NE : 0) + e0;
#pragma unroll
    for (int i = 0; i < 8; ++i) {
      const int r = cg + i * 8;
      raw[i] = ((const float4*)(h + (size_t)idxb[r] * HD + koff))[cl];
    }
  };
  auto writeH = [&](_Float16* buf) {
#pragma unroll
    for (int i = 0; i < 8; ++i)
      *(h4*)&buf[(cg + i * 8) * BSTRIDE + cl * 4] = f2h4(raw[i]);
  };

  f32x4 acc[4][4];
#pragma unroll
  for (int m = 0; m < 4; ++m)
#pragma unroll
    for (int n = 0; n < 4; ++n) acc[m][n] = (f32x4){0.f, 0.f, 0.f, 0.f};

  const int afrag = l15 * BSTRIDE + lg * 8;   // + m*16*BSTRIDE + ks*32

#define MFMA_PHASE(BUF, WF, KSG0, NKS, KSTRIDE)                                     \
  _Pragma("unroll")                                                                 \
  for (int ks = 0; ks < NKS; ++ks) {                                                \
    h8 b[4];                                                                        \
    _Pragma("unroll")                                                               \
    for (int n = 0; n < 4; ++n)                                                     \
      b[n] = *(const h8*)&WF[(size_t)(((w * 4 + n) * KSTRIDE + KSG0 + ks) * 64 + l) * 8]; \
    _Pragma("unroll")                                                               \
    for (int m = 0; m < 4; ++m) {                                                   \
      const h8 a = *(const h8*)&BUF[afrag + m * 16 * BSTRIDE + ks * 32];            \
      _Pragma("unroll")                                                             \
      for (int n = 0; n < 4; ++n)                                                   \
        acc[m][n] = __builtin_amdgcn_mfma_f32_16x16x32_f16(a, b[n], acc[m][n], 0, 0, 0); \
    }                                                                               \
  }

  // ---- S0: h[row] k[0,128) ----
  loadH(0, 0);
  writeH(B0);
  __syncthreads();

  // ---- iter 0: prefetch S1, MFMA S0 ----
  loadH(0, 128);
  MFMA_PHASE(B0, g_W1f, 0, 4, 18)
  writeH(B1);
  __syncthreads();

  // ---- iter 1: prefetch S2, MFMA S1 ----
  loadH(1, 0);
  MFMA_PHASE(B1, g_W1f, 4, 4, 18)
  writeH(B0);
  __syncthreads();

  // ---- iter 2: prefetch S3, MFMA S2 ----
  loadH(1, 128);
  MFMA_PHASE(B0, g_W1f, 8, 4, 18)
  writeH(B1);
  __syncthreads();

  // ---- iter 3: prefetch S4 (eattr), MFMA S3 ----
  float4 rawE[4];
  {
    const int rE = t >> 4;       // 0..15, rows rE+16i
    const int cE = t & 15;
#pragma unroll
    for (int i = 0; i < 4; ++i)
      rawE[i] = ((const float4*)(eattr + (size_t)(e0 + rE + i * 16) * EDIM))[cE];
  }
  MFMA_PHASE(B1, g_W1f, 12, 4, 18)
  {
    const int rE = t >> 4, cE = t & 15;
#pragma unroll
    for (int i = 0; i < 4; ++i)
      *(h4*)&B0[(rE + i * 16) * BSTRIDE + cE * 4] = f2h4(rawE[i]);
  }
  __syncthreads();

  // ---- iter 4: MFMA S4 (K=64) ----
  MFMA_PHASE(B0, g_W1f, 16, 2, 18)
  __syncthreads();

  // ---- hid = relu(acc + b1) -> B0 (cols 0..127) / B1 (cols 128..255) ----
  {
    _Float16* hbuf = (w < 2) ? B0 : B1;
#pragma unroll
    for (int n = 0; n < 4; ++n) {
      const int c = w * 64 + n * 16 + l15;
      const float bb = b1[c];
      const int cc = c & 127;
#pragma unroll
      for (int m = 0; m < 4; ++m)
#pragma unroll
        for (int r = 0; r < 4; ++r) {
          const int e = m * 16 + lg * 4 + r;
          float v = acc[m][n][r] + bb;
          v = v > 0.f ? v : 0.f;
          hbuf[e * BSTRIDE + cc] = (_Float16)v;
        }
    }
  }
  __syncthreads();

  // ---- layer 2: phase A (B0, k 0..127), phase B (B1, k 128..255) ----
  f32x4 acc2[4][4];
#pragma unroll
  for (int m = 0; m < 4; ++m)
#pragma unroll
    for (int n = 0; n < 4; ++n) acc2[m][n] = (f32x4){0.f, 0.f, 0.f, 0.f};

#define MFMA2_PHASE(BUF, KSG0)                                                      \
  _Pragma("unroll")                                                                 \
  for (int ks = 0; ks < 4; ++ks) {                                                  \
    h8 b[4];                                                                        \
    _Pragma("unroll")                                                               \
    for (int n = 0; n < 4; ++n)                                                     \
      b[n] = *(const h8*)&g_W2f[(size_t)(((w * 4 + n) * 8 + KSG0 + ks) * 64 + l) * 8]; \
    _Pragma("unroll")                                                               \
    for (int m = 0; m < 4; ++m) {                                                   \
      const h8 a = *(const h8*)&BUF[afrag + m * 16 * BSTRIDE + ks * 32];            \
      _Pragma("unroll")                                                             \
      for (int n = 0; n < 4; ++n)                                                   \
        acc2[m][n] = __builtin_amdgcn_mfma_f32_16x16x32_f16(a, b[n], acc2[m][n], 0, 0, 0); \
    }                                                                               \
  }

  MFMA2_PHASE(B0, 0)
  MFMA2_PHASE(B1, 4)

  // ---- scatter-add msg + b2 into agg (edge ids re-read: broadcast L1 hits) ----
#pragma unroll
  for (int n = 0; n < 4; ++n) {
    const int c = w * 64 + n * 16 + l15;
    const float bb = b2[c];
#pragma unroll
    for (int m = 0; m < 4; ++m)
#pragma unroll
      for (int r = 0; r < 4; ++r) {
        const int e = m * 16 + lg * 4 + r;
        const int node = ei[e0 + e];
        unsafeAtomicAdd(&agg[(size_t)node * HD + c], acc2[m][n][r] + bb);
      }
  }
}

// -------------------- fused GRU update (MFMA fp16, unchanged) --------------------
#define ASTRIDE 264

__global__ __launch_bounds__(256, 4) void gru_kernel(
    const float* __restrict__ h, const float* __restrict__ agg,
    const float* __restrict__ b_ih, const float* __restrict__ b_hh,
    float* __restrict__ out)
{
  __shared__ _Float16 A[64 * ASTRIDE];

  const int t   = threadIdx.x;
  const int w   = t >> 6;
  const int l   = t & 63;
  const int l15 = l & 15;
  const int lg  = l >> 4;
  const int nb  = blockIdx.x * 64;
  const int c0  = blockIdx.y * 64;
  const int cf0 = c0 >> 4;

  f32x4 ar[4], az[4], ax[4], ah[4];
#pragma unroll
  for (int n = 0; n < 4; ++n) {
    ar[n] = (f32x4){0.f, 0.f, 0.f, 0.f}; az[n] = (f32x4){0.f, 0.f, 0.f, 0.f};
    ax[n] = (f32x4){0.f, 0.f, 0.f, 0.f}; ah[n] = (f32x4){0.f, 0.f, 0.f, 0.f};
  }

  const int afrag_base = (w * 16 + l15) * ASTRIDE + lg * 8;

#pragma unroll
  for (int s = 0; s < 2; ++s) {
    __syncthreads();
    const float* src = s == 0 ? agg : h;
#pragma unroll
    for (int i = 0; i < 16; ++i) {
      const int e = i * 4 + w;
      int node = nb + e; if (node >= NN) node = NN - 1;
      float4 v = ((const float4*)(src + (size_t)node * HD))[l];
      *(h4*)&A[e * ASTRIDE + l * 4] = f2h4(v);
    }
    __syncthreads();
    for (int ks = 0; ks < 8; ++ks) {
      const int ksg = s * 8 + ks;
      const h8 a = *(const h8*)&A[afrag_base + ks * 32];
      h8 br[4], bz[4], bn[4];
#pragma unroll
      for (int n = 0; n < 4; ++n) {
        br[n] = *(const h8*)&g_Wrzf[(size_t)(((cf0 + n) * 16 + ksg) * 64 + l) * 8];
        bz[n] = *(const h8*)&g_Wrzf[(size_t)(((16 + cf0 + n) * 16 + ksg) * 64 + l) * 8];
        bn[n] = (s == 0)
          ? *(const h8*)&g_Wnxf[(size_t)(((cf0 + n) * 8 + ks) * 64 + l) * 8]
          : *(const h8*)&g_Wnhf[(size_t)(((cf0 + n) * 8 + ks) * 64 + l) * 8];
      }
#pragma unroll
      for (int n = 0; n < 4; ++n) {
        ar[n] = __builtin_amdgcn_mfma_f32_16x16x32_f16(a, br[n], ar[n], 0, 0, 0);
        az[n] = __builtin_amdgcn_mfma_f32_16x16x32_f16(a, bz[n], az[n], 0, 0, 0);
        if (s == 0) ax[n] = __builtin_amdgcn_mfma_f32_16x16x32_f16(a, bn[n], ax[n], 0, 0, 0);
        else        ah[n] = __builtin_amdgcn_mfma_f32_16x16x32_f16(a, bn[n], ah[n], 0, 0, 0);
      }
    }
  }

#pragma unroll
  for (int n = 0; n < 4; ++n) {
    const int c = c0 + n * 16 + l15;
    const float br_ = b_ih[c] + b_hh[c];
    const float bz_ = b_ih[HD + c] + b_hh[HD + c];
    const float bxn = b_ih[2 * HD + c];
    const float bhn = b_hh[2 * HD + c];
#pragma unroll
    for (int r = 0; r < 4; ++r) {
      const int node = nb + w * 16 + lg * 4 + r;
      if (node < NN) {
        const float rg = 1.f / (1.f + __expf(-(ar[n][r] + br_)));
        const float zg = 1.f / (1.f + __expf(-(az[n][r] + bz_)));
        const float ng = tanhf(ax[n][r] + bxn + rg * (ah[n][r] + bhn));
        const float hv = h[(size_t)node * HD + c];
        out[(size_t)node * HD + c] = (1.f - zg) * ng + zg * hv;
      }
    }
  }
}

extern "C" void kernel_launch(void* const* d_in, const int* in_sizes, int n_in,
                              void* d_out, int out_size, void* d_ws, size_t ws_size,
                              hipStream_t stream)
{
  const float* h     = (const float*)d_in[0];
  const int*   ei    = (const int*)d_in[1];
  const float* eattr = (const float*)d_in[2];
  const float* W1    = (const float*)d_in[3];
  const float* b1    = (const float*)d_in[4];
  const float* W2    = (const float*)d_in[5];
  const float* b2    = (const float*)d_in[6];
  const float* W_ih  = (const float*)d_in[7];
  const float* b_ih  = (const float*)d_in[8];
  const float* W_hh  = (const float*)d_in[9];
  const float* b_hh  = (const float*)d_in[10];
  float* out = (float*)d_out;
  float* agg = (float*)d_ws;   // [NN][HD] f32 = 20.5 MB

  hipMemsetAsync(agg, 0, (size_t)NN * HD * sizeof(float), stream);
  cvt_kernel<<<(1184 * 64 + 255) / 256, 256, 0, stream>>>(W1, W2, W_ih, W_hh);
  edge_kernel<<<NE / 64, 256, 0, stream>>>(h, ei, eattr, b1, b2, agg);
  gru_kernel<<<dim3((NN + 63) / 64, HD / 64), 256, 0, stream>>>(h, agg, b_ih, b_hh, out);
}